// Round 2
// baseline (2428.865 us; speedup 1.0000x reference)
//
#include <hip/hip_runtime.h>
#include <hip/hip_bf16.h>

#define T_TOK 1024
#define HID 1024
#define NH 16
#define NKV 4
#define HDIM 64
#define NE 64
#define NG 8
#define INTER 512
#define QKV_N 1536

// ---------------- RMSNorm (f32 input) ----------------
__global__ void rms_kernel(const float* __restrict__ x, const float* __restrict__ w,
                           float* __restrict__ out) {
    int t = blockIdx.x, tid = threadIdx.x;
    __shared__ float red[256];
    const float* xp = x + (size_t)t * HID;
    float v[4]; float ss = 0.f;
    for (int j = 0; j < 4; ++j) { v[j] = xp[tid * 4 + j]; ss += v[j] * v[j]; }
    red[tid] = ss; __syncthreads();
    for (int s = 128; s > 0; s >>= 1) { if (tid < s) red[tid] += red[tid + s]; __syncthreads(); }
    float r = rsqrtf(red[0] / (float)HID + 1e-6f);
    for (int j = 0; j < 4; ++j)
        out[(size_t)t * HID + tid * 4 + j] = v[j] * r * w[tid * 4 + j];
}

// ---------------- Tiled GEMM: C(MxN) = A(MxK) @ B(KxN) [+ addend] ----------------
__global__ void gemm_f32(const float* __restrict__ A, const float* __restrict__ B,
                         float* __restrict__ C, const float* __restrict__ addend,
                         int M, int N, int K) {
    __shared__ float As[16][65];  // [k][m]
    __shared__ float Bs[16][64];  // [k][n]
    int tid = threadIdx.x;
    int tx = tid & 15, ty = tid >> 4;
    int row0 = blockIdx.y * 64, col0 = blockIdx.x * 64;
    float acc[4][4] = {};
    for (int k0 = 0; k0 < K; k0 += 16) {
        for (int i = tid; i < 64 * 16; i += 256) {
            int r = i >> 4, kk = i & 15;
            As[kk][r] = A[(size_t)(row0 + r) * K + k0 + kk];
        }
        for (int i = tid; i < 16 * 64; i += 256) {
            int kk = i >> 6, c = i & 63;
            Bs[kk][c] = B[(size_t)(k0 + kk) * N + col0 + c];
        }
        __syncthreads();
        for (int kk = 0; kk < 16; ++kk) {
            float a[4], b[4];
            for (int i = 0; i < 4; ++i) a[i] = As[kk][ty * 4 + i];
            for (int j = 0; j < 4; ++j) b[j] = Bs[kk][tx * 4 + j];
            for (int i = 0; i < 4; ++i)
                for (int j = 0; j < 4; ++j) acc[i][j] += a[i] * b[j];
        }
        __syncthreads();
    }
    for (int i = 0; i < 4; ++i) {
        int r = row0 + ty * 4 + i;
        for (int j = 0; j < 4; ++j) {
            int c = col0 + tx * 4 + j;
            float v = acc[i][j];
            if (addend) v += addend[(size_t)r * N + c];
            C[(size_t)r * N + c] = v;
        }
    }
}

// ---------------- per-head RMSNorm + RoPE on q,k (in-place in qkv f32) ----------------
__global__ void qk_rope_kernel(float* __restrict__ qkv, const int* __restrict__ pos,
                               const float* __restrict__ qw, const float* __restrict__ kw) {
    int b = blockIdx.x;
    int t = b / (NH + NKV), hh = b % (NH + NKV);
    int lane = threadIdx.x;
    bool isq = hh < NH;
    int off = isq ? hh * HDIM : NH * HDIM + (hh - NH) * HDIM;
    const float* w = isq ? qw : kw;
    float* p = qkv + (size_t)t * QKV_N + off;
    float x = p[lane];
    float ss = x * x;
    for (int m = 1; m < 64; m <<= 1) ss += __shfl_xor(ss, m, 64);
    float r = rsqrtf(ss / (float)HDIM + 1e-6f);
    x = x * r * w[lane];
    float partner = __shfl_xor(x, 32, 64);
    int i = lane & 31;
    float freq = expf(-(float)i * (9.21034037198f / 32.f));  // 10000^(-i/32)
    float f = (float)pos[t] * freq;
    float c = cosf(f), s = sinf(f);
    float outv = (lane < 32) ? (x * c - partner * s) : (x * c + partner * s);
    p[lane] = outv;
}

// ---------------- attention: one block per (t, head) ----------------
__global__ void attn_kernel(const float* __restrict__ qkv, float* __restrict__ attn_out) {
    int t = blockIdx.x, hh = blockIdx.y;
    int kh = hh >> 2;
    __shared__ float sq[64];
    __shared__ float sc[T_TOK];
    __shared__ float red[256];
    __shared__ float po[4][64];
    int tid = threadIdx.x;
    const float* qp = qkv + (size_t)t * QKV_N + hh * HDIM;
    if (tid < 64) sq[tid] = qp[tid];
    __syncthreads();
    int L = t + 1;
    float lmax = -1e30f;
    for (int s = tid; s < L; s += 256) {
        const float* kp = qkv + (size_t)s * QKV_N + NH * HDIM + kh * HDIM;
        float dot = 0.f;
        for (int d = 0; d < 64; ++d) dot += sq[d] * kp[d];
        dot *= 0.125f;  // 1/sqrt(64)
        sc[s] = dot;
        lmax = fmaxf(lmax, dot);
    }
    red[tid] = lmax; __syncthreads();
    for (int s = 128; s > 0; s >>= 1) { if (tid < s) red[tid] = fmaxf(red[tid], red[tid + s]); __syncthreads(); }
    float mx = red[0]; __syncthreads();
    float lsum = 0.f;
    for (int s = tid; s < L; s += 256) { float e = expf(sc[s] - mx); sc[s] = e; lsum += e; }
    red[tid] = lsum; __syncthreads();
    for (int s = 128; s > 0; s >>= 1) { if (tid < s) red[tid] += red[tid + s]; __syncthreads(); }
    float inv = 1.f / red[0];
    int grp = tid >> 6, lane = tid & 63;
    float acc = 0.f;
    for (int s = grp; s < L; s += 4)
        acc += sc[s] * qkv[(size_t)s * QKV_N + (NH + NKV) * HDIM + kh * HDIM + lane];
    po[grp][lane] = acc;
    __syncthreads();
    if (tid < 64) {
        float o = (po[0][tid] + po[1][tid] + po[2][tid] + po[3][tid]) * inv;
        attn_out[(size_t)t * HID + hh * HDIM + tid] = o;
    }
}

// ---------------- router: logits, softmax, group top-1, scatter ----------------
__global__ void route_kernel(const float* __restrict__ h2, const float* __restrict__ Wg,
                             int* __restrict__ cnt, int* __restrict__ lst_tok,
                             int* __restrict__ lst_pair, float* __restrict__ pair_w) {
    int t = blockIdx.x, j = threadIdx.x;  // 64 threads
    const float* hp = h2 + (size_t)t * HID;
    float acc = 0.f;
    for (int k = 0; k < HID; ++k) acc += hp[k] * Wg[(size_t)k * NE + j];
    float mx = acc;
    for (int m = 1; m < 64; m <<= 1) mx = fmaxf(mx, __shfl_xor(mx, m, 64));
    float e = expf(acc - mx);
    float sm = e;
    for (int m = 1; m < 64; m <<= 1) sm += __shfl_xor(sm, m, 64);
    float p = e / sm;
    // top-1 within each group of 8 lanes (tie -> lowest index, matching top_k)
    float bp = p; int bi = j;
    for (int m = 1; m < 8; m <<= 1) {
        float op = __shfl_xor(bp, m, 64);
        int oi = __shfl_xor(bi, m, 64);
        if (op > bp || (op == bp && oi < bi)) { bp = op; bi = oi; }
    }
    __shared__ float gw[8]; __shared__ int gi[8];
    if ((j & 7) == 0) { gw[j >> 3] = bp; gi[j >> 3] = bi; }
    __syncthreads();
    if (j < 8) {
        float tw = gw[j];
        float wsum = tw;
        for (int m = 1; m < 8; m <<= 1) wsum += __shfl_xor(wsum, m, 64);
        float w = tw / wsum;
        int ei = gi[j];
        int pos = atomicAdd(&cnt[ei], 1);
        lst_tok[ei * T_TOK + pos] = t;
        lst_pair[ei * T_TOK + pos] = t * 8 + j;
        pair_w[t * 8 + j] = w;
    }
}

// ---------------- MoE gate_up + SiLU*up*w, grouped by expert, 64-token tiles ----------------
__global__ void moe_gateup_kernel(const float* __restrict__ h2, const float* __restrict__ Wgu,
                                  const int* __restrict__ cnt, const int* __restrict__ lst_tok,
                                  const int* __restrict__ lst_pair, const float* __restrict__ pair_w,
                                  float* __restrict__ act) {
    int e = blockIdx.x;
    int i0 = blockIdx.y * 64;  // over INTER
    int n = cnt[e];
    if (n == 0) return;
    int tid = threadIdx.x;
    int tx = tid & 15, ty = tid >> 4;
    __shared__ float Hs[16][65];
    __shared__ float Gs[16][64];
    __shared__ float Us[16][64];
    __shared__ int s_tok[64]; __shared__ int s_pair[64];
    const float* W = Wgu + (size_t)e * HID * (2 * INTER);
    for (int tt = 0; tt < n; tt += 64) {
        if (tid < 64) {
            bool ok = (tt + tid) < n;
            s_tok[tid]  = ok ? lst_tok[e * T_TOK + tt + tid] : -1;
            s_pair[tid] = ok ? lst_pair[e * T_TOK + tt + tid] : -1;
        }
        __syncthreads();
        float accg[4][4] = {}, accu[4][4] = {};
        for (int k0 = 0; k0 < HID; k0 += 16) {
            for (int i = tid; i < 64 * 16; i += 256) {
                int r = i >> 4, kk = i & 15;
                int tok = s_tok[r];
                Hs[kk][r] = (tok >= 0) ? h2[(size_t)tok * HID + k0 + kk] : 0.f;
            }
            for (int i = tid; i < 1024; i += 256) {
                int kk = i >> 6, c = i & 63;
                Gs[kk][c] = W[(size_t)(k0 + kk) * (2 * INTER) + i0 + c];
                Us[kk][c] = W[(size_t)(k0 + kk) * (2 * INTER) + INTER + i0 + c];
            }
            __syncthreads();
            for (int kk = 0; kk < 16; ++kk) {
                float a[4], g[4], u[4];
                for (int i = 0; i < 4; ++i) a[i] = Hs[kk][ty * 4 + i];
                for (int j = 0; j < 4; ++j) { g[j] = Gs[kk][tx * 4 + j]; u[j] = Us[kk][tx * 4 + j]; }
                for (int i = 0; i < 4; ++i)
                    for (int j = 0; j < 4; ++j) { accg[i][j] += a[i] * g[j]; accu[i][j] += a[i] * u[j]; }
            }
            __syncthreads();
        }
        for (int i = 0; i < 4; ++i) {
            int r = ty * 4 + i;
            int pr = s_pair[r];
            if (pr >= 0) {
                float w = pair_w[pr];
                float* ap = act + (size_t)pr * INTER + i0 + tx * 4;
                for (int j = 0; j < 4; ++j) {
                    float g = accg[i][j], u = accu[i][j];
                    float silu = g / (1.f + expf(-g));
                    ap[j] = silu * u * w;
                }
            }
        }
        __syncthreads();
    }
}

// ---------------- MoE down: 64-token tiles, atomicAdd into f32 accumulator ----------------
__global__ void moe_down_kernel(const float* __restrict__ act, const float* __restrict__ Wd,
                                const int* __restrict__ cnt, const int* __restrict__ lst_tok,
                                const int* __restrict__ lst_pair, float* __restrict__ acc_out) {
    int e = blockIdx.x;
    int c0 = blockIdx.y * 64;  // over HID
    int n = cnt[e];
    if (n == 0) return;
    int tid = threadIdx.x;
    int tx = tid & 15, ty = tid >> 4;
    __shared__ float As[16][65];
    __shared__ float Ws[16][64];
    __shared__ int s_tok[64]; __shared__ int s_pair[64];
    const float* W = Wd + (size_t)e * INTER * HID;
    for (int tt = 0; tt < n; tt += 64) {
        if (tid < 64) {
            bool ok = (tt + tid) < n;
            s_tok[tid]  = ok ? lst_tok[e * T_TOK + tt + tid] : -1;
            s_pair[tid] = ok ? lst_pair[e * T_TOK + tt + tid] : -1;
        }
        __syncthreads();
        float acc[4][4] = {};
        for (int k0 = 0; k0 < INTER; k0 += 16) {
            for (int i = tid; i < 64 * 16; i += 256) {
                int r = i >> 4, kk = i & 15;
                int pr = s_pair[r];
                As[kk][r] = (pr >= 0) ? act[(size_t)pr * INTER + k0 + kk] : 0.f;
            }
            for (int i = tid; i < 1024; i += 256) {
                int kk = i >> 6, c = i & 63;
                Ws[kk][c] = W[(size_t)(k0 + kk) * HID + c0 + c];
            }
            __syncthreads();
            for (int kk = 0; kk < 16; ++kk) {
                float a[4], b[4];
                for (int i = 0; i < 4; ++i) a[i] = As[kk][ty * 4 + i];
                for (int j = 0; j < 4; ++j) b[j] = Ws[kk][tx * 4 + j];
                for (int i = 0; i < 4; ++i)
                    for (int j = 0; j < 4; ++j) acc[i][j] += a[i] * b[j];
            }
            __syncthreads();
        }
        for (int i = 0; i < 4; ++i) {
            int r = ty * 4 + i;
            int tok = s_tok[r];
            if (tok >= 0) {
                for (int j = 0; j < 4; ++j)
                    atomicAdd(&acc_out[(size_t)tok * HID + c0 + tx * 4 + j], acc[i][j]);
            }
        }
        __syncthreads();
    }
}

// ---------------- final: out = x + moe ----------------
__global__ void final_add_kernel(const float* __restrict__ x, const float* __restrict__ moe,
                                 float* __restrict__ out) {
    int i = blockIdx.x * 256 + threadIdx.x;
    out[i] = x[i] + moe[i];
}

extern "C" void kernel_launch(void* const* d_in, const int* in_sizes, int n_in,
                              void* d_out, int out_size, void* d_ws, size_t ws_size,
                              hipStream_t stream) {
    const int*   positions = (const int*)d_in[0];
    const float* hidden    = (const float*)d_in[1];
    const float* Wqkv      = (const float*)d_in[2];
    const float* Wo        = (const float*)d_in[3];
    const float* q_norm_w  = (const float*)d_in[4];
    const float* k_norm_w  = (const float*)d_in[5];
    const float* in_ln_w   = (const float*)d_in[6];
    const float* post_ln_w = (const float*)d_in[7];
    const float* Wg        = (const float*)d_in[8];
    const float* Wgu       = (const float*)d_in[9];
    const float* Wd        = (const float*)d_in[10];
    float* out = (float*)d_out;

    char* ws = (char*)d_ws;
    size_t off = 0;
    auto alloc = [&](size_t bytes) { char* p = ws + off; off += (bytes + 255) & ~(size_t)255; return p; };
    // bufA: h -> attn_out -> h2 (lifetimes disjoint)
    float* bufA     = (float*)alloc((size_t)T_TOK * HID * 4);
    // bufB: qkv (6MB, dead after attn) then act (16MB) overlap
    float* bufB     = (float*)alloc((size_t)T_TOK * 8 * INTER * 4);
    float* x        = (float*)alloc((size_t)T_TOK * HID * 4);
    float* acc_moe  = (float*)alloc((size_t)T_TOK * HID * 4);
    int*   cnt      = (int*)alloc(NE * 4);
    int*   lst_tok  = (int*)alloc((size_t)NE * T_TOK * 4);
    int*   lst_pair = (int*)alloc((size_t)NE * T_TOK * 4);
    float* pair_w   = (float*)alloc((size_t)T_TOK * 8 * 4);

    float* h        = bufA;
    float* attn_out = bufA;
    float* h2       = bufA;
    float* qkv      = bufB;
    float* act      = bufB;

    hipMemsetAsync(cnt, 0, NE * 4, stream);
    hipMemsetAsync(acc_moe, 0, (size_t)T_TOK * HID * 4, stream);

    rms_kernel<<<T_TOK, 256, 0, stream>>>(hidden, in_ln_w, h);
    gemm_f32<<<dim3(QKV_N / 64, T_TOK / 64), 256, 0, stream>>>(h, Wqkv, qkv, nullptr, T_TOK, QKV_N, HID);
    qk_rope_kernel<<<T_TOK * (NH + NKV), 64, 0, stream>>>(qkv, positions, q_norm_w, k_norm_w);
    attn_kernel<<<dim3(T_TOK, NH), 256, 0, stream>>>(qkv, attn_out);
    gemm_f32<<<dim3(HID / 64, T_TOK / 64), 256, 0, stream>>>(attn_out, Wo, x, hidden, T_TOK, HID, HID);
    rms_kernel<<<T_TOK, 256, 0, stream>>>(x, post_ln_w, h2);
    route_kernel<<<T_TOK, 64, 0, stream>>>(h2, Wg, cnt, lst_tok, lst_pair, pair_w);
    moe_gateup_kernel<<<dim3(NE, INTER / 64), 256, 0, stream>>>(h2, Wgu, cnt, lst_tok, lst_pair, pair_w, act);
    moe_down_kernel<<<dim3(NE, HID / 64), 256, 0, stream>>>(act, Wd, cnt, lst_tok, lst_pair, acc_moe);
    final_add_kernel<<<(T_TOK * HID) / 256, 256, 0, stream>>>(x, acc_moe, out);
}